// Round 8
// baseline (6138.128 us; speedup 1.0000x reference)
//
#include <hip/hip_runtime.h>
#include <stdint.h>
#include <stddef.h>

// ---------------- problem constants ----------------
#define Bb 64
#define Tt 1024
#define Hh 512
#define Ll 4
#define Gg 2048                 // 4*H
#define NSTEPS (Tt + Ll - 1)    // 1027 wavefront steps
#define NBLK 256                // 4 layers x 4 batch-slices x 16 j-slices
#define NTHR 256                // 4 waves (each owns a k-quarter)
#define GRP 64                  // blocks per layer group
#define FLAG_STRIDE 32          // u32 per flag slot = 128 B (own cacheline)
#define FLAG_BYTES (Ll * GRP * FLAG_STRIDE * 4)        // 32 KB of epoch flags
#define HBUF_ELEMS ((size_t)Ll * 2 * Bb * Hh)          // bf16 elements
#define PRS 133                 // partial-buffer row stride (f32): 128 + 5 -> ~2-way banks

typedef __bf16 bfrag __attribute__((ext_vector_type(8)));   // 8 bf16 = 4 VGPR (MFMA A/B)
typedef float f32x4 __attribute__((ext_vector_type(4)));    // MFMA C/D
typedef uint64_t u64;

__device__ __forceinline__ float sigm(float x) { return 1.0f / (1.0f + __expf(-x)); }
__device__ __forceinline__ float tanh_(float x) {
    float ax = fabsf(x);
    float e = __expf(-2.0f * ax);
    float r = (1.0f - e) / (1.0f + e);
    return copysignf(r, x);
}

__device__ __forceinline__ bfrag cvt8(const float4& x0, const float4& x1) {
    bfrag a;
    a[0] = (__bf16)x0.x; a[1] = (__bf16)x0.y; a[2] = (__bf16)x0.z; a[3] = (__bf16)x0.w;
    a[4] = (__bf16)x1.x; a[5] = (__bf16)x1.y; a[6] = (__bf16)x1.z; a[7] = (__bf16)x1.w;
    return a;
}

// Issue one 16B uncached (coherent-point) load WITHOUT waiting.
__device__ __forceinline__ bfrag load_h16_async(const __bf16* p) {
    bfrag r;
    asm volatile("global_load_dwordx4 %0, %1, off sc0 sc1"
                 : "=v"(r) : "v"(p));
    return r;
}

// Throttled spin (verified r6/r7 structure).
__device__ __forceinline__ void spin_ge(const uint32_t* p, uint32_t v) {
    if (__hip_atomic_load(p, __ATOMIC_RELAXED, __HIP_MEMORY_SCOPE_SYSTEM) >= v) return;
    for (;;) {
        __builtin_amdgcn_s_sleep(8);
        if (__hip_atomic_load(p, __ATOMIC_RELAXED, __HIP_MEMORY_SCOPE_SYSTEM) >= v) return;
    }
}

__global__ __launch_bounds__(NTHR, 1)
void lstm_persistent(const float* __restrict__ inp,    // [B,T,H] fp32
                     const float* __restrict__ Wih,    // [L,4H,H] fp32
                     const float* __restrict__ Whh,    // [L,4H,H] fp32
                     const float* __restrict__ bih,    // [L,4H] fp32
                     const float* __restrict__ bhh,    // [L,4H] fp32
                     float* __restrict__ out,          // fp32: [T,B,H] + L*(h,c)[B,H]
                     uint32_t* __restrict__ flags,     // [L][GRP][FLAG_STRIDE] epoch flags (zeroed)
                     __bf16* __restrict__ hbuf)        // [L][2][B][H] bf16 (zeroed)
{
    const int tid  = threadIdx.x;
    const int bx   = blockIdx.x;
    const int l    = bx >> 6;        // layer 0..3
    const int rem  = bx & 63;
    const int r    = rem >> 4;       // batch-slice 0..3 (rows 16r..16r+15)
    const int qj   = rem & 15;       // j-slice 0..15 (hidden cols qj*32..+31)
    const int J0   = qj * 32;
    const int w    = tid >> 6;       // wave id: owns k-quarter [128w, 128w+128)
    const int lane = tid & 63;
    const int ln16 = lane & 15;
    const int quad = lane >> 4;
    const int k0   = 128 * w;        // k-quarter base (bf16 elements)

    // LDS: 34048 (k-partials) + 2112 (cst) + 528 (bias) = 36688 B  (<160 KiB)
    __shared__ float part[4][16][PRS];   // [wave][row][gate-col 0..127], stride-133
    __shared__ float cstS[16][33];       // cell state fp32 (thread-private slots)
    __shared__ float biasLds[132];       // 128 gate-cols

    // ---- weight preload: fp32 global -> bf16 B-fragments in REGISTERS ----
    // wave w holds ALL 128 gate-cols (8 tiles x 16) for its k-quarter.
    bfrag wI[8][4], wH[8][4];
#pragma unroll
    for (int t8 = 0; t8 < 8; ++t8) {
        const int gc   = t8 * 16 + ln16;      // gate-col 0..127
        const int gate = gc >> 5, j = gc & 31;
        const size_t grow = (size_t)l * Gg + gate * Hh + J0 + j;
        const float* wi = Wih + grow * Hh + k0;
        const float* wh = Whh + grow * Hh + k0;
#pragma unroll
        for (int kk = 0; kk < 4; ++kk) {
            const int k = kk * 32 + quad * 8;
            wI[t8][kk] = cvt8(*reinterpret_cast<const float4*>(wi + k),
                              *reinterpret_cast<const float4*>(wi + k + 4));
            wH[t8][kk] = cvt8(*reinterpret_cast<const float4*>(wh + k),
                              *reinterpret_cast<const float4*>(wh + k + 4));
        }
    }
    if (tid < 128) {
        const int gate = tid >> 5, j = tid & 31;
        const int col = gate * Hh + J0 + j;
        biasLds[tid] = bih[l * Gg + col] + bhh[l * Gg + col];
    }
    __syncthreads();

    uint32_t* flagOwn = flags + (size_t)l * GRP * FLAG_STRIDE;
    uint32_t* flagLo  = flagOwn - (size_t)GRP * FLAG_STRIDE;   // valid only if l>0
    uint32_t* flagHi  = flagOwn + (size_t)GRP * FLAG_STRIDE;   // valid only if l<Ll-1

    // cell mapping: thread -> (row = tid>>4, col pair 2c,2c+1 within block's 32)
    const int crow  = tid >> 4;          // 0..15
    const int cc    = tid & 15;          // 0..15 -> cols 2cc, 2cc+1
    const int bglob = 16 * r + crow;

    for (int s = 0; s < NSTEPS; ++s) {
        const int t = s - l;
        const bool active = (t >= 0) && (t < Tt);

        if (active) {
            const int p = (s - 1) & 1;   // parity slot written last step

            // ---------- direct A-fragment loads (no LDS): ONE latency exposure ----------
            bfrag ax[4], ah[4];
            const __bf16* hb = hbuf + ((size_t)(l * 2 + p) * Bb + 16 * r + ln16) * Hh + k0;
            if (l == 0) {
#pragma unroll
                for (int kk = 0; kk < 4; ++kk)
                    ah[kk] = load_h16_async(hb + kk * 32 + quad * 8);
                const float* xb = inp + ((size_t)(16 * r + ln16) * Tt + t) * Hh + k0;
                float4 x0[4], x1[4];
#pragma unroll
                for (int kk = 0; kk < 4; ++kk) {
                    x0[kk] = *reinterpret_cast<const float4*>(xb + kk * 32 + quad * 8);
                    x1[kk] = *reinterpret_cast<const float4*>(xb + kk * 32 + quad * 8 + 4);
                }
                asm volatile("s_waitcnt vmcnt(0)" ::: "memory");
                __builtin_amdgcn_sched_barrier(0);   // rule #18
#pragma unroll
                for (int kk = 0; kk < 4; ++kk) ax[kk] = cvt8(x0[kk], x1[kk]);
            } else {
                const __bf16* xbh = hbuf + ((size_t)((l - 1) * 2 + p) * Bb + 16 * r + ln16) * Hh + k0;
#pragma unroll
                for (int kk = 0; kk < 4; ++kk)
                    ax[kk] = load_h16_async(xbh + kk * 32 + quad * 8);
#pragma unroll
                for (int kk = 0; kk < 4; ++kk)
                    ah[kk] = load_h16_async(hb + kk * 32 + quad * 8);
                asm volatile("s_waitcnt vmcnt(0)" ::: "memory");
                __builtin_amdgcn_sched_barrier(0);   // rule #18
            }

            // ---------- MFMA: 8 tiles x (4 kk x 2 mats), k-quarter partials ----------
            f32x4 acc[8];
#pragma unroll
            for (int t8 = 0; t8 < 8; ++t8) acc[t8] = (f32x4){0.f, 0.f, 0.f, 0.f};
#pragma unroll
            for (int t8 = 0; t8 < 8; ++t8) {
#pragma unroll
                for (int kk = 0; kk < 4; ++kk) {
                    acc[t8] = __builtin_amdgcn_mfma_f32_16x16x32_bf16(ax[kk], wI[t8][kk], acc[t8], 0, 0, 0);
                    acc[t8] = __builtin_amdgcn_mfma_f32_16x16x32_bf16(ah[kk], wH[t8][kk], acc[t8], 0, 0, 0);
                }
            }

            // ---------- write k-partials to LDS (stride-133: ~2-way banks, free) ----------
            // D layout: col=lane&15, row=quad*4+reg (m89-verified)
#pragma unroll
            for (int t8 = 0; t8 < 8; ++t8) {
#pragma unroll
                for (int r2 = 0; r2 < 4; ++r2) {
                    part[w][quad * 4 + r2][t8 * 16 + ln16] = acc[t8][r2];
                }
            }
        }
        __syncthreads();   // k-partials visible to cell threads

        if (active) {
            // ---------- elementwise LSTM cell: sum 4 wave-partials + bias ----------
            float hv[2], cv[2];
#pragma unroll
            for (int u2 = 0; u2 < 2; ++u2) {
                const int j = 2 * cc + u2;
                float iv = part[0][crow][j]      + part[1][crow][j]      + part[2][crow][j]      + part[3][crow][j]      + biasLds[j];
                float fv = part[0][crow][32 + j] + part[1][crow][32 + j] + part[2][crow][32 + j] + part[3][crow][32 + j] + biasLds[32 + j];
                float gv = part[0][crow][64 + j] + part[1][crow][64 + j] + part[2][crow][64 + j] + part[3][crow][64 + j] + biasLds[64 + j];
                float ov = part[0][crow][96 + j] + part[1][crow][96 + j] + part[2][crow][96 + j] + part[3][crow][96 + j] + biasLds[96 + j];
                float cold = (t == 0) ? 0.0f : cstS[crow][j];
                float cnew = sigm(fv) * cold + sigm(iv) * tanh_(gv);
                float h = sigm(ov) * tanh_(cnew);
                cstS[crow][j] = cnew;
                cv[u2] = cnew;
                hv[u2] = h;
            }
            const int hcol = J0 + 2 * cc;

            // publish bf16 h (write-through to coherent point)
            union { __bf16 h[2]; uint32_t u; } pk;
            pk.h[0] = (__bf16)hv[0];
            pk.h[1] = (__bf16)hv[1];
            uint32_t* hdst = (uint32_t*)(hbuf + ((size_t)(l * 2 + (s & 1)) * Bb + bglob) * Hh + hcol);
            __hip_atomic_store(hdst, pk.u, __ATOMIC_RELAXED, __HIP_MEMORY_SCOPE_SYSTEM);

            // ---- fp32 outputs ----
            if (l == Ll - 1) {
                float2 xv = make_float2(hv[0], hv[1]);
                *reinterpret_cast<float2*>(out + ((size_t)t * Bb + bglob) * Hh + hcol) = xv;
            }
            if (t == Tt - 1) {
                const size_t xend = (size_t)Tt * Bb * Hh;
                float2 hv2 = make_float2(hv[0], hv[1]);
                float2 cv2 = make_float2(cv[0], cv[1]);
                *reinterpret_cast<float2*>(out + xend + ((size_t)(2 * l) * Bb + bglob) * Hh + hcol) = hv2;
                *reinterpret_cast<float2*>(out + xend + ((size_t)(2 * l + 1) * Bb + bglob) * Hh + hcol) = cv2;
            }
        }

        // ---------- neighborhood sync: verified r2/r6/r7 structure, unchanged ----------
        // __syncthreads drains every wave's vmcnt => all write-through h stores
        // have reached the coherent point before the flag store below.
        __syncthreads();
        if (s < NSTEPS - 1) {
            const uint32_t want = (uint32_t)(s + 1);
            if (tid == 0) {
                __hip_atomic_store(&flagOwn[rem * FLAG_STRIDE], want,
                                   __ATOMIC_RELAXED, __HIP_MEMORY_SCOPE_SYSTEM);
            }
            if (w == 0) {
                spin_ge(&flagOwn[lane * FLAG_STRIDE], want);       // own layer done step s
            } else if (w == 1 && l > 0) {
                spin_ge(&flagLo[lane * FLAG_STRIDE], want);        // layer below done (x input)
            } else if (w == 2 && l < Ll - 1) {
                spin_ge(&flagHi[lane * FLAG_STRIDE], want);        // layer above consumed parity slot
            }
            asm volatile("" ::: "memory");
        }
        __syncthreads();
    }
}

extern "C" void kernel_launch(void* const* d_in, const int* in_sizes, int n_in,
                              void* d_out, int out_size, void* d_ws, size_t ws_size,
                              hipStream_t stream) {
    const float* inp = (const float*)d_in[0];
    const float* Wih = (const float*)d_in[1];
    const float* Whh = (const float*)d_in[2];
    const float* bih = (const float*)d_in[3];
    const float* bhh = (const float*)d_in[4];
    float* out = (float*)d_out;

    uint32_t* flags = (uint32_t*)d_ws;
    __bf16*   hbuf  = (__bf16*)((char*)d_ws + FLAG_BYTES);

    // zero epoch flags + h double-buffers (ws usage: 32 KB + 512 KB)
    hipMemsetAsync(d_ws, 0, FLAG_BYTES + HBUF_ELEMS * sizeof(__bf16), stream);

    lstm_persistent<<<dim3(NBLK), dim3(NTHR), 0, stream>>>(inp, Wih, Whh, bih, bhh,
                                                           out, flags, hbuf);
}

// Round 9
// 4848.207 us; speedup vs baseline: 1.2661x; 1.2661x over previous
//
#include <hip/hip_runtime.h>
#include <stdint.h>
#include <stddef.h>

// ---------------- problem constants ----------------
#define Bb 64
#define Tt 1024
#define Hh 512
#define Ll 4
#define Gg 2048                 // 4*H
#define NSTEPS (Tt + Ll - 1)    // 1027 wavefront steps
#define NBLK 256                // 4 layers x 4 batch-slices x 16 j-slices
#define NTHR 512                // 8 waves (each owns a k-eighth)
#define GRP 64                  // blocks per layer group
#define FLAG_STRIDE 32          // u32 per flag slot = 128 B (own cacheline)
#define FLAG_BYTES (Ll * GRP * FLAG_STRIDE * 4)        // 32 KB of epoch flags
#define HBUF_ELEMS ((size_t)Ll * 2 * Bb * Hh)          // bf16 elements
#define PRS 133                 // partial-buffer row stride (f32): 128 + 5 -> ~2-way banks

typedef __bf16 bfrag __attribute__((ext_vector_type(8)));   // 8 bf16 = 4 VGPR (MFMA A/B)
typedef float f32x4 __attribute__((ext_vector_type(4)));    // MFMA C/D
typedef uint64_t u64;

__device__ __forceinline__ float sigm(float x) { return 1.0f / (1.0f + __expf(-x)); }
__device__ __forceinline__ float tanh_(float x) {
    float ax = fabsf(x);
    float e = __expf(-2.0f * ax);
    float r = (1.0f - e) / (1.0f + e);
    return copysignf(r, x);
}

__device__ __forceinline__ bfrag cvt8(const float4& x0, const float4& x1) {
    bfrag a;
    a[0] = (__bf16)x0.x; a[1] = (__bf16)x0.y; a[2] = (__bf16)x0.z; a[3] = (__bf16)x0.w;
    a[4] = (__bf16)x1.x; a[5] = (__bf16)x1.y; a[6] = (__bf16)x1.z; a[7] = (__bf16)x1.w;
    return a;
}

// Issue one 16B uncached (coherent-point) load WITHOUT waiting.
__device__ __forceinline__ bfrag load_h16_async(const __bf16* p) {
    bfrag r;
    asm volatile("global_load_dwordx4 %0, %1, off sc0 sc1"
                 : "=v"(r) : "v"(p));
    return r;
}

// Throttled spin (verified r6/r7/r8 structure; tighter backoff, poll set is 4x smaller now).
__device__ __forceinline__ void spin_ge(const uint32_t* p, uint32_t v) {
    if (__hip_atomic_load(p, __ATOMIC_RELAXED, __HIP_MEMORY_SCOPE_SYSTEM) >= v) return;
    for (;;) {
        __builtin_amdgcn_s_sleep(4);
        if (__hip_atomic_load(p, __ATOMIC_RELAXED, __HIP_MEMORY_SCOPE_SYSTEM) >= v) return;
    }
}

__global__ __launch_bounds__(NTHR, 1)
void lstm_persistent(const float* __restrict__ inp,    // [B,T,H] fp32
                     const float* __restrict__ Wih,    // [L,4H,H] fp32
                     const float* __restrict__ Whh,    // [L,4H,H] fp32
                     const float* __restrict__ bih,    // [L,4H] fp32
                     const float* __restrict__ bhh,    // [L,4H] fp32
                     float* __restrict__ out,          // fp32: [T,B,H] + L*(h,c)[B,H]
                     uint32_t* __restrict__ flags,     // [L][GRP][FLAG_STRIDE] epoch flags (zeroed)
                     __bf16* __restrict__ hbuf)        // [L][2][B][H] bf16 (zeroed)
{
    const int tid  = threadIdx.x;
    const int bx   = blockIdx.x;
    const int l    = bx >> 6;        // layer 0..3
    const int rem  = bx & 63;
    const int r    = rem >> 4;       // batch-slice 0..3 (rows 16r..16r+15)
    const int qj   = rem & 15;       // j-slice 0..15 (hidden cols qj*32..+31)
    const int J0   = qj * 32;
    const int w    = tid >> 6;       // wave id 0..7: owns k-eighth [64w, 64w+64)
    const int lane = tid & 63;
    const int ln16 = lane & 15;
    const int quad = lane >> 4;
    const int k0   = 64 * w;         // k-eighth base (bf16 elements)

    // LDS: 68096 (k-partials) + 2112 (cst) + 528 (bias) = 70736 B  (<160 KiB)
    __shared__ float part[8][16][PRS];   // [wave][row][gate-col 0..127], stride-133
    __shared__ float cstS[16][33];       // cell state fp32 (thread-private slots)
    __shared__ float biasLds[132];       // 128 gate-cols

    // ---- weight preload: fp32 global -> bf16 B-fragments in REGISTERS ----
    // wave w holds ALL 128 gate-cols (8 tiles x 16) for its k-eighth: 128 VGPRs total.
    bfrag wI[8][2], wH[8][2];
#pragma unroll
    for (int t8 = 0; t8 < 8; ++t8) {
        const int gc   = t8 * 16 + ln16;      // gate-col 0..127
        const int gate = gc >> 5, j = gc & 31;
        const size_t grow = (size_t)l * Gg + gate * Hh + J0 + j;
        const float* wi = Wih + grow * Hh + k0;
        const float* wh = Whh + grow * Hh + k0;
#pragma unroll
        for (int kk = 0; kk < 2; ++kk) {
            const int k = kk * 32 + quad * 8;
            wI[t8][kk] = cvt8(*reinterpret_cast<const float4*>(wi + k),
                              *reinterpret_cast<const float4*>(wi + k + 4));
            wH[t8][kk] = cvt8(*reinterpret_cast<const float4*>(wh + k),
                              *reinterpret_cast<const float4*>(wh + k + 4));
        }
    }
    if (tid < 128) {
        const int gate = tid >> 5, j = tid & 31;
        const int col = gate * Hh + J0 + j;
        biasLds[tid] = bih[l * Gg + col] + bhh[l * Gg + col];
    }
    __syncthreads();

    uint32_t* flagOwn = flags + (size_t)l * GRP * FLAG_STRIDE;
    uint32_t* flagLo  = flagOwn - (size_t)GRP * FLAG_STRIDE;   // valid only if l>0
    uint32_t* flagHi  = flagOwn + (size_t)GRP * FLAG_STRIDE;   // valid only if l<Ll-1

    // r-cohort flag bases: block (l,r,qj) only depends on blocks (l',r,*) - 16 flags each
    const int cohortBase = (r * 16) * FLAG_STRIDE;

    // cell mapping (tid<256): thread -> (row = tid>>4, col pair 2cc,2cc+1)
    const int crow  = (tid & 255) >> 4;  // 0..15
    const int cc    = tid & 15;          // 0..15 -> cols 2cc, 2cc+1
    const int bglob = 16 * r + crow;

    for (int s = 0; s < NSTEPS; ++s) {
        const int t = s - l;
        const bool active = (t >= 0) && (t < Tt);

        if (active) {
            const int p = (s - 1) & 1;   // parity slot written last step

            // ---------- direct A-fragment loads (no LDS): ONE latency exposure ----------
            bfrag ax[2], ah[2];
            const __bf16* hb = hbuf + ((size_t)(l * 2 + p) * Bb + 16 * r + ln16) * Hh + k0;
            if (l == 0) {
#pragma unroll
                for (int kk = 0; kk < 2; ++kk)
                    ah[kk] = load_h16_async(hb + kk * 32 + quad * 8);
                const float* xb = inp + ((size_t)(16 * r + ln16) * Tt + t) * Hh + k0;
                float4 x0[2], x1[2];
#pragma unroll
                for (int kk = 0; kk < 2; ++kk) {
                    x0[kk] = *reinterpret_cast<const float4*>(xb + kk * 32 + quad * 8);
                    x1[kk] = *reinterpret_cast<const float4*>(xb + kk * 32 + quad * 8 + 4);
                }
                asm volatile("s_waitcnt vmcnt(0)" ::: "memory");
                __builtin_amdgcn_sched_barrier(0);   // rule #18
#pragma unroll
                for (int kk = 0; kk < 2; ++kk) ax[kk] = cvt8(x0[kk], x1[kk]);
            } else {
                const __bf16* xbh = hbuf + ((size_t)((l - 1) * 2 + p) * Bb + 16 * r + ln16) * Hh + k0;
#pragma unroll
                for (int kk = 0; kk < 2; ++kk)
                    ax[kk] = load_h16_async(xbh + kk * 32 + quad * 8);
#pragma unroll
                for (int kk = 0; kk < 2; ++kk)
                    ah[kk] = load_h16_async(hb + kk * 32 + quad * 8);
                asm volatile("s_waitcnt vmcnt(0)" ::: "memory");
                __builtin_amdgcn_sched_barrier(0);   // rule #18
            }

            // ---------- MFMA: 8 tiles x (2 kk x 2 mats) = 32 MFMAs, k-eighth partials ----------
            f32x4 acc[8];
#pragma unroll
            for (int t8 = 0; t8 < 8; ++t8) acc[t8] = (f32x4){0.f, 0.f, 0.f, 0.f};
#pragma unroll
            for (int t8 = 0; t8 < 8; ++t8) {
#pragma unroll
                for (int kk = 0; kk < 2; ++kk) {
                    acc[t8] = __builtin_amdgcn_mfma_f32_16x16x32_bf16(ax[kk], wI[t8][kk], acc[t8], 0, 0, 0);
                    acc[t8] = __builtin_amdgcn_mfma_f32_16x16x32_bf16(ah[kk], wH[t8][kk], acc[t8], 0, 0, 0);
                }
            }

            // ---------- write k-partials to LDS ----------
            // D layout: col=lane&15, row=quad*4+reg (m89-verified)
#pragma unroll
            for (int t8 = 0; t8 < 8; ++t8) {
#pragma unroll
                for (int r2 = 0; r2 < 4; ++r2) {
                    part[w][quad * 4 + r2][t8 * 16 + ln16] = acc[t8][r2];
                }
            }
        }
        __syncthreads();   // k-partials visible to cell threads

        if (active && tid < 256) {
            // ---------- elementwise LSTM cell: sum 8 wave-partials + bias ----------
            float hv[2], cv[2];
#pragma unroll
            for (int u2 = 0; u2 < 2; ++u2) {
                const int j = 2 * cc + u2;
                float iv = biasLds[j], fv = biasLds[32 + j], gv = biasLds[64 + j], ov = biasLds[96 + j];
#pragma unroll
                for (int ww = 0; ww < 8; ++ww) {
                    iv += part[ww][crow][j];
                    fv += part[ww][crow][32 + j];
                    gv += part[ww][crow][64 + j];
                    ov += part[ww][crow][96 + j];
                }
                float cold = (t == 0) ? 0.0f : cstS[crow][j];
                float cnew = sigm(fv) * cold + sigm(iv) * tanh_(gv);
                float h = sigm(ov) * tanh_(cnew);
                cstS[crow][j] = cnew;
                cv[u2] = cnew;
                hv[u2] = h;
            }
            const int hcol = J0 + 2 * cc;

            // publish bf16 h (write-through to coherent point)
            union { __bf16 h[2]; uint32_t u; } pk;
            pk.h[0] = (__bf16)hv[0];
            pk.h[1] = (__bf16)hv[1];
            uint32_t* hdst = (uint32_t*)(hbuf + ((size_t)(l * 2 + (s & 1)) * Bb + bglob) * Hh + hcol);
            __hip_atomic_store(hdst, pk.u, __ATOMIC_RELAXED, __HIP_MEMORY_SCOPE_SYSTEM);

            // ---- fp32 outputs ----
            if (l == Ll - 1) {
                float2 xv = make_float2(hv[0], hv[1]);
                *reinterpret_cast<float2*>(out + ((size_t)t * Bb + bglob) * Hh + hcol) = xv;
            }
            if (t == Tt - 1) {
                const size_t xend = (size_t)Tt * Bb * Hh;
                float2 hv2 = make_float2(hv[0], hv[1]);
                float2 cv2 = make_float2(cv[0], cv[1]);
                *reinterpret_cast<float2*>(out + xend + ((size_t)(2 * l) * Bb + bglob) * Hh + hcol) = hv2;
                *reinterpret_cast<float2*>(out + xend + ((size_t)(2 * l + 1) * Bb + bglob) * Hh + hcol) = cv2;
            }
        }

        // ---------- r-cohort sync: same protocol, narrowed dependency set ----------
        // __syncthreads drains every wave's vmcnt => all write-through h stores
        // have reached the coherent point before the flag store below.
        __syncthreads();
        if (s < NSTEPS - 1) {
            const uint32_t want = (uint32_t)(s + 1);
            if (tid == 0) {
                __hip_atomic_store(&flagOwn[rem * FLAG_STRIDE], want,
                                   __ATOMIC_RELAXED, __HIP_MEMORY_SCOPE_SYSTEM);
            }
            // each spinning wave polls its group's 16 r-cohort flags (lane<16)
            if (w == 0) {
                if (lane < 16) spin_ge(&flagOwn[cohortBase + lane * FLAG_STRIDE], want);
            } else if (w == 1 && l > 0) {
                if (lane < 16) spin_ge(&flagLo[cohortBase + lane * FLAG_STRIDE], want);
            } else if (w == 2 && l < Ll - 1) {
                if (lane < 16) spin_ge(&flagHi[cohortBase + lane * FLAG_STRIDE], want);
            }
            asm volatile("" ::: "memory");
        }
        __syncthreads();
    }
}

extern "C" void kernel_launch(void* const* d_in, const int* in_sizes, int n_in,
                              void* d_out, int out_size, void* d_ws, size_t ws_size,
                              hipStream_t stream) {
    const float* inp = (const float*)d_in[0];
    const float* Wih = (const float*)d_in[1];
    const float* Whh = (const float*)d_in[2];
    const float* bih = (const float*)d_in[3];
    const float* bhh = (const float*)d_in[4];
    float* out = (float*)d_out;

    uint32_t* flags = (uint32_t*)d_ws;
    __bf16*   hbuf  = (__bf16*)((char*)d_ws + FLAG_BYTES);

    // zero epoch flags + h double-buffers (ws usage: 32 KB + 512 KB)
    hipMemsetAsync(d_ws, 0, FLAG_BYTES + HBUF_ELEMS * sizeof(__bf16), stream);

    lstm_persistent<<<dim3(NBLK), dim3(NTHR), 0, stream>>>(inp, Wih, Whh, bih, bhh,
                                                           out, flags, hbuf);
}